// Round 1
// baseline (147.563 us; speedup 1.0000x reference)
//
#include <hip/hip_runtime.h>
#include <stdint.h>

typedef __bf16 bf16x8 __attribute__((ext_vector_type(8)));
typedef float f32x4 __attribute__((ext_vector_type(4)));
typedef unsigned short u16;
typedef const __attribute__((address_space(1))) void* as1_cvp;
typedef __attribute__((address_space(3))) void* as3_vp;

__device__ __forceinline__ u16 f2bf(float f) {
  union { float f; unsigned u; } v; v.f = f;
  unsigned r = v.u + 0x7fffu + ((v.u >> 16) & 1u);
  return (u16)(r >> 16);
}

// ---- idx histogram + exclusive scan (4 options) ----
__global__ void hist_kernel(const int* __restrict__ idx, int n,
                            int* __restrict__ starts, int* __restrict__ cursors) {
  __shared__ int cnt[4];
  if (threadIdx.x < 4) { cnt[threadIdx.x] = 0; cursors[threadIdx.x] = 0; }
  __syncthreads();
  for (int i = threadIdx.x; i < n; i += blockDim.x)
    atomicAdd(&cnt[idx[i] & 3], 1);
  __syncthreads();
  if (threadIdx.x == 0) {
    int s = 0;
    for (int g = 0; g < 4; ++g) { starts[g] = s; s += cnt[g]; }
    starts[4] = s;
  }
}

// ---- per-row: rank within group, write perm, convert row to bf16 (sorted) ----
__global__ __launch_bounds__(256) void permute_convert(
    const float* __restrict__ x, const int* __restrict__ idx,
    const int* __restrict__ starts, int* cursors,
    int* __restrict__ perm, u16* __restrict__ Xs) {
  const int b = blockIdx.x;
  __shared__ int s_pos;
  if (threadIdx.x == 0) {
    const int g = idx[b] & 3;
    const int r = atomicAdd(&cursors[g], 1);
    const int p = starts[g] + r;
    perm[p] = b;
    s_pos = p;
  }
  __syncthreads();
  const int p = s_pos;
  const float4 v = ((const float4*)(x + (size_t)b * 1024))[threadIdx.x];
  ushort4 u;
  u.x = f2bf(v.x); u.y = f2bf(v.y); u.z = f2bf(v.z); u.w = f2bf(v.w);
  ((ushort4*)(Xs + (size_t)p * 1024))[threadIdx.x] = u;
}

// ---- W [O][K][N] f32 -> WT [O][N][K] bf16 (tiled transpose) ----
__global__ __launch_bounds__(256) void transpose_convert(
    const float* __restrict__ W, u16* __restrict__ WT, int K, int N) {
  __shared__ float tile[64][65];
  const int o = blockIdx.z;
  const float* Wo = W + (size_t)o * K * N;
  u16* WTo = WT + (size_t)o * N * K;
  const int k0 = blockIdx.y * 64, n0 = blockIdx.x * 64;
  const int tr = threadIdx.x >> 6, tc = threadIdx.x & 63;
  #pragma unroll
  for (int r = tr; r < 64; r += 4)
    tile[r][tc] = Wo[(size_t)(k0 + r) * N + (n0 + tc)];
  __syncthreads();
  #pragma unroll
  for (int r = tr; r < 64; r += 4)
    WTo[(size_t)(n0 + r) * K + (k0 + tc)] = f2bf(tile[tc][r]);
}

// ---- grouped GEMM: C[M,N] = A_sorted[M,K] @ WT[o][N,K]^T (+bias) ----
// m97 structure: 128x128 tile, BK=32, 4 waves, each wave 64x64 (4x4 frags of 16x16x32)
template <int EPI, int K, int N>
__global__ __launch_bounds__(256) void gemm_kernel(
    const u16* __restrict__ A, const u16* __restrict__ BT,
    const float* __restrict__ bias, const int* __restrict__ starts,
    const int* __restrict__ perm, u16* __restrict__ outH,
    float* __restrict__ outF) {
  __shared__ char smem[16384];  // A tile 8KB [128][32]bf16, B tile 8KB [128][32]bf16
  const int o = blockIdx.z;
  const int g_start = starts[o];
  const int g_end = starts[o + 1];
  const int m_start = g_start + blockIdx.y * 128;
  if (m_start >= g_end) return;
  const int n_start = blockIdx.x * 128;
  const u16* Bo = BT + (size_t)o * N * K;

  const int tid = threadIdx.x;
  const int w = tid >> 6;    // wave 0..3
  const int l = tid & 63;
  const int wm = w >> 1, wn = w & 1;

  // staging: per issue i in {0,1}: linear byte = i*4096 + w*1024 + l*16
  //   -> tile row = i*64 + w*16 + l/4, k-elem offset = (l&3)*8
  const int srow = (w << 4) + (l >> 2);
  const int skol = (l & 3) << 3;

  // fragment read offset within a 16-row frag region: row=(l&15), kgroup=(l>>4)
  const int lane_off = ((l & 15) << 6) + ((l >> 4) << 4);  // bytes, rows are 64B
  char* const ldsA = smem;
  char* const ldsB = smem + 8192;

  f32x4 acc[4][4] = {};

  const int nK = K >> 5;
  for (int kt = 0; kt < nK; ++kt) {
    const int kbase = kt << 5;
    #pragma unroll
    for (int i = 0; i < 2; ++i) {
      const int row = i * 64 + srow;
      int ar = m_start + row;
      if (ar >= g_end) ar = g_end - 1;  // clamp; stores predicated later
      const u16* ga = A + (size_t)ar * K + kbase + skol;
      __builtin_amdgcn_global_load_lds((as1_cvp)ga,
          (as3_vp)(ldsA + i * 4096 + w * 1024), 16, 0, 0);
      const u16* gb = Bo + (size_t)(n_start + row) * K + kbase + skol;
      __builtin_amdgcn_global_load_lds((as1_cvp)gb,
          (as3_vp)(ldsB + i * 4096 + w * 1024), 16, 0, 0);
    }
    __syncthreads();
    bf16x8 af[4], bfr[4];
    #pragma unroll
    for (int a = 0; a < 4; ++a)
      af[a] = *(const bf16x8*)(ldsA + ((wm * 64 + a * 16) << 6) + lane_off);
    #pragma unroll
    for (int b = 0; b < 4; ++b)
      bfr[b] = *(const bf16x8*)(ldsB + ((wn * 64 + b * 16) << 6) + lane_off);
    #pragma unroll
    for (int a = 0; a < 4; ++a)
      #pragma unroll
      for (int b = 0; b < 4; ++b)
        acc[a][b] = __builtin_amdgcn_mfma_f32_16x16x32_bf16(af[a], bfr[b], acc[a][b], 0, 0, 0);
    __syncthreads();
  }

  // epilogue: C/D layout col = l&15, row = (l>>4)*4 + r  [m89-verified]
  const int row_l = (l >> 4) << 2;
  const int col_l = l & 15;
  #pragma unroll
  for (int a = 0; a < 4; ++a) {
    #pragma unroll
    for (int b = 0; b < 4; ++b) {
      const int n = n_start + wn * 64 + b * 16 + col_l;
      const float bv = bias[n];
      #pragma unroll
      for (int r = 0; r < 4; ++r) {
        const int p = m_start + wm * 64 + a * 16 + row_l + r;
        if (p < g_end) {
          const float v = acc[a][b][r] + bv;
          if (EPI == 0) {
            outH[(size_t)p * N + n] = f2bf(v);
          } else {
            outF[(size_t)perm[p] * N + n] = v;
          }
        }
      }
    }
  }
}

extern "C" void kernel_launch(void* const* d_in, const int* in_sizes, int n_in,
                              void* d_out, int out_size, void* d_ws, size_t ws_size,
                              hipStream_t stream) {
  (void)n_in; (void)out_size; (void)ws_size;
  const float* x   = (const float*)d_in[0];
  const int*   idx = (const int*)d_in[1];
  const float* W1  = (const float*)d_in[2];
  const float* b1  = (const float*)d_in[3];
  const float* W2  = (const float*)d_in[4];
  const float* b2  = (const float*)d_in[5];
  float* out = (float*)d_out;

  const int B = in_sizes[1];  // 2048
  const int L0 = 1024, L1 = 2048, L2 = 1024, O = 4;

  // workspace layout
  char* ws = (char*)d_ws;
  u16* W1T    = (u16*)(ws);                    // O*L1*L0 bf16 = 16 MB  (layout [o][N=L1][K=L0])
  u16* W2T    = (u16*)(ws + 16777216);         // O*L2*L1 bf16 = 16 MB  (layout [o][N=L2][K=L1])
  u16* Xs     = (u16*)(ws + 33554432);         // B*L0 bf16 = 4 MB (sorted rows)
  u16* Hs     = (u16*)(ws + 37748736);         // B*L1 bf16 = 8 MB (sorted rows)
  int* perm   = (int*)(ws + 46137344);         // B ints
  int* starts = (int*)(ws + 46137344 + 8192);  // 5 ints (+pad)
  int* cursors = starts + 8;                   // 4 ints

  hist_kernel<<<1, 64, 0, stream>>>(idx, B, starts, cursors);
  transpose_convert<<<dim3(L1 / 64, L0 / 64, O), 256, 0, stream>>>(W1, W1T, L0, L1);
  transpose_convert<<<dim3(L2 / 64, L1 / 64, O), 256, 0, stream>>>(W2, W2T, L1, L2);
  permute_convert<<<B, 256, 0, stream>>>(x, idx, starts, cursors, perm, Xs);

  const int mtiles = (B + 127) / 128;
  gemm_kernel<0, 1024, 2048><<<dim3(L1 / 128, mtiles, O), 256, 0, stream>>>(
      Xs, W1T, b1 /*option 0 rows first*/, starts, perm, Hs, nullptr);
  gemm_kernel<1, 2048, 1024><<<dim3(L2 / 128, mtiles, O), 256, 0, stream>>>(
      Hs, W2T, b2, starts, perm, nullptr, out);
}

// Round 3
// 124.428 us; speedup vs baseline: 1.1859x; 1.1859x over previous
//
#include <hip/hip_runtime.h>
#include <stdint.h>

typedef __bf16 bf16x8 __attribute__((ext_vector_type(8)));
typedef float f32x4 __attribute__((ext_vector_type(4)));
typedef unsigned short u16;
typedef const __attribute__((address_space(1))) void* as1_cvp;
typedef __attribute__((address_space(3))) void* as3_vp;

__device__ __forceinline__ u16 f2bf(float f) {
  union { float f; unsigned u; } v; v.f = f;
  unsigned r = v.u + 0x7fffu + ((v.u >> 16) & 1u);
  return (u16)(r >> 16);
}

// ---- idx histogram + exclusive scan (4 options) ----
__global__ __launch_bounds__(256) void hist_kernel(const int* __restrict__ idx, int n,
                            int* __restrict__ starts, int* __restrict__ cursors) {
  __shared__ int cnt[4];
  const int t = threadIdx.x;
  if (t < 4) { cnt[t] = 0; cursors[t] = 0; }
  __syncthreads();
  int c0 = 0, c1 = 0, c2 = 0, c3 = 0;
  for (int i = t; i < n; i += 256) {
    const int g = idx[i] & 3;
    c0 += (g == 0); c1 += (g == 1); c2 += (g == 2); c3 += (g == 3);
  }
  if (c0) atomicAdd(&cnt[0], c0);
  if (c1) atomicAdd(&cnt[1], c1);
  if (c2) atomicAdd(&cnt[2], c2);
  if (c3) atomicAdd(&cnt[3], c3);
  __syncthreads();
  if (t == 0) {
    int s = 0;
    for (int g = 0; g < 4; ++g) { starts[g] = s; s += cnt[g]; }
    starts[4] = s;
  }
}

// ---- per-row: rank within group, write perm, convert row to bf16 (sorted) ----
__global__ __launch_bounds__(256) void permute_convert(
    const float* __restrict__ x, const int* __restrict__ idx,
    const int* __restrict__ starts, int* cursors,
    int* __restrict__ perm, u16* __restrict__ Xs) {
  const int b = blockIdx.x;
  __shared__ int s_pos;
  if (threadIdx.x == 0) {
    const int g = idx[b] & 3;
    const int r = atomicAdd(&cursors[g], 1);
    const int p = starts[g] + r;
    perm[p] = b;
    s_pos = p;
  }
  __syncthreads();
  const int p = s_pos;
  const float4 v = ((const float4*)(x + (size_t)b * 1024))[threadIdx.x];
  ushort4 u;
  u.x = f2bf(v.x); u.y = f2bf(v.y); u.z = f2bf(v.z); u.w = f2bf(v.w);
  ((ushort4*)(Xs + (size_t)p * 1024))[threadIdx.x] = u;
}

// ---- W [O][K][N] f32 -> WT [O][N][K] bf16 (tiled transpose, vectorized) ----
__global__ __launch_bounds__(256) void transpose_convert(
    const float* __restrict__ W, u16* __restrict__ WT, int K, int N) {
  __shared__ float tile[64][65];
  const int o = blockIdx.z;
  const float* Wo = W + (size_t)o * K * N;
  u16* WTo = WT + (size_t)o * N * K;
  const int k0 = blockIdx.y * 64, n0 = blockIdx.x * 64;
  const int rr = threadIdx.x >> 4, cc = threadIdx.x & 15;
  #pragma unroll
  for (int j = 0; j < 4; ++j) {
    const int r = j * 16 + rr;
    const float4 v = *(const float4*)(Wo + (size_t)(k0 + r) * N + n0 + cc * 4);
    tile[r][cc * 4 + 0] = v.x; tile[r][cc * 4 + 1] = v.y;
    tile[r][cc * 4 + 2] = v.z; tile[r][cc * 4 + 3] = v.w;
  }
  __syncthreads();
  #pragma unroll
  for (int j = 0; j < 4; ++j) {
    const int nrow = j * 16 + rr;
    ushort4 u;
    u.x = f2bf(tile[cc * 4 + 0][nrow]);
    u.y = f2bf(tile[cc * 4 + 1][nrow]);
    u.z = f2bf(tile[cc * 4 + 2][nrow]);
    u.w = f2bf(tile[cc * 4 + 3][nrow]);
    *(ushort4*)(WTo + (size_t)(n0 + nrow) * K + k0 + cc * 4) = u;
  }
}

// ---- grouped GEMM: C[M,N] = A_sorted[M,K] @ WT[o][N,K]^T ----
// tile M64 x N128, BK=64, 4 waves (2x2), each wave 32x64 (2x4 frags, kk-loop 2)
// EPI 0: write bf16 (sorted) + bias.  EPI 1: write f32 split-K partial.
template <int EPI, int KT, int NN, int S, int NTN, int NTM>
__global__ __launch_bounds__(256) void gemm_kernel(
    const u16* __restrict__ A, const u16* __restrict__ BT,
    const float* __restrict__ bias, const int* __restrict__ starts,
    u16* __restrict__ outH, float* __restrict__ outP, int batchB) {
  __shared__ char smem[24576];  // A [64][64]bf16 8KB, B [128][64]bf16 16KB

  // XCD-chunked bijective swizzle (nwg % 8 == 0), n fastest -> L2 panel reuse
  const int nwg = NTN * NTM * 4 * S;
  const int q = nwg >> 3;
  const int bid = blockIdx.x;
  const int swz = (bid & 7) * q + (bid >> 3);
  const int n_t = swz % NTN;
  const int m_t = (swz / NTN) % NTM;
  const int og = swz / (NTN * NTM);
  const int o = og & 3;
  const int s = og >> 2;

  const int g0 = starts[o], g1 = starts[o + 1];
  const int m_start = g0 + m_t * 64;
  if (m_start >= g1) return;
  const int n_start = n_t * 128;
  const int kb0 = s * (KT / S);
  const u16* Bo = BT + (size_t)o * NN * KT;

  const int tid = threadIdx.x;
  const int w = tid >> 6;  // wave 0..3
  const int l = tid & 63;
  const int wm = w >> 1, wn = w & 1;
  const int l8 = l & 7, ld8 = l >> 3;

  char* const ldsA = smem;
  char* const ldsB = smem + 8192;

  // staging source pointers (1KB chunk per wave per issue; LDS dest = base + lane*16)
  const u16* pA[2];
  #pragma unroll
  for (int j = 0; j < 2; ++j) {
    int r = m_start + (j * 4 + w) * 8 + ld8;
    if (r >= g1) r = g1 - 1;  // clamp (predicated at epilogue)
    pA[j] = A + (size_t)r * KT + kb0 + l8 * 8;
  }
  const u16* pB[4];
  #pragma unroll
  for (int j = 0; j < 4; ++j) {
    const int nr = n_start + (j * 4 + w) * 8 + ld8;
    pB[j] = Bo + (size_t)nr * KT + kb0 + l8 * 8;
  }

  // fragment read offsets: rows are 128B (64 k-elems)
  const int frow = (l & 15) << 7;         // (l&15)*128
  const int fkg = (l >> 4) << 4;          // kgroup*16 bytes
  char* const fA = ldsA + frow + fkg + wm * 32 * 128;
  char* const fB = ldsB + frow + fkg + wn * 64 * 128;

  f32x4 acc[2][4] = {};

  const int nK = (KT / S) >> 6;
  for (int kt = 0; kt < nK; ++kt) {
    #pragma unroll
    for (int j = 0; j < 2; ++j)
      __builtin_amdgcn_global_load_lds((as1_cvp)pA[j],
          (as3_vp)(ldsA + (j * 4 + w) * 1024), 16, 0, 0);
    #pragma unroll
    for (int j = 0; j < 4; ++j)
      __builtin_amdgcn_global_load_lds((as1_cvp)pB[j],
          (as3_vp)(ldsB + (j * 4 + w) * 1024), 16, 0, 0);
    __syncthreads();

    bf16x8 af[2][2], bfr[4][2];
    #pragma unroll
    for (int a = 0; a < 2; ++a)
      #pragma unroll
      for (int kk = 0; kk < 2; ++kk)
        af[a][kk] = *(const bf16x8*)(fA + a * 2048 + kk * 64);
    #pragma unroll
    for (int b = 0; b < 4; ++b)
      #pragma unroll
      for (int kk = 0; kk < 2; ++kk)
        bfr[b][kk] = *(const bf16x8*)(fB + b * 2048 + kk * 64);
    #pragma unroll
    for (int kk = 0; kk < 2; ++kk)
      #pragma unroll
      for (int a = 0; a < 2; ++a)
        #pragma unroll
        for (int b = 0; b < 4; ++b)
          acc[a][b] = __builtin_amdgcn_mfma_f32_16x16x32_bf16(af[a][kk], bfr[b][kk], acc[a][b], 0, 0, 0);
    __syncthreads();

    #pragma unroll
    for (int j = 0; j < 2; ++j) pA[j] += 64;
    #pragma unroll
    for (int j = 0; j < 4; ++j) pB[j] += 64;
  }

  // epilogue: C/D layout col = l&15, row = (l>>4)*4 + r  [m89-verified]
  const int col_l = l & 15;
  const int row_l = (l >> 4) << 2;
  #pragma unroll
  for (int a = 0; a < 2; ++a) {
    #pragma unroll
    for (int b = 0; b < 4; ++b) {
      const int n = n_start + wn * 64 + b * 16 + col_l;
      float bv = 0.f;
      if (EPI == 0) bv = bias[n];
      #pragma unroll
      for (int r = 0; r < 4; ++r) {
        const int p = m_start + wm * 32 + a * 16 + row_l + r;
        if (p < g1) {
          if (EPI == 0) {
            outH[(size_t)p * NN + n] = f2bf(acc[a][b][r] + bv);
          } else {
            outP[((size_t)(s * batchB + p)) * NN + n] = acc[a][b][r];
          }
        }
      }
    }
  }
}

// ---- split-K reduce + bias + scatter (deterministic fixed-order adds) ----
__global__ __launch_bounds__(256) void reduce_kernel(
    const float* __restrict__ part, const float* __restrict__ b2,
    const int* __restrict__ perm, float* __restrict__ out, int batchB) {
  const int p = blockIdx.x;
  const int t = threadIdx.x;
  const float4 v0 = ((const float4*)(part + (size_t)p * 1024))[t];
  const float4 v1 = ((const float4*)(part + (size_t)(batchB + p) * 1024))[t];
  const float4 bv = ((const float4*)b2)[t];
  float4 r;
  r.x = v0.x + v1.x + bv.x;
  r.y = v0.y + v1.y + bv.y;
  r.z = v0.z + v1.z + bv.z;
  r.w = v0.w + v1.w + bv.w;
  ((float4*)(out + (size_t)perm[p] * 1024))[t] = r;
}

extern "C" void kernel_launch(void* const* d_in, const int* in_sizes, int n_in,
                              void* d_out, int out_size, void* d_ws, size_t ws_size,
                              hipStream_t stream) {
  (void)n_in; (void)out_size; (void)ws_size;
  const float* x   = (const float*)d_in[0];
  const int*   idx = (const int*)d_in[1];
  const float* W1  = (const float*)d_in[2];
  const float* b1  = (const float*)d_in[3];
  const float* W2  = (const float*)d_in[4];
  const float* b2  = (const float*)d_in[5];
  float* out = (float*)d_out;

  const int B = in_sizes[1];  // 2048
  const int L0 = 1024, L1 = 2048, L2 = 1024, O = 4;

  // workspace layout (44.05 MB; part aliases W1T which is dead after GEMM1)
  char* ws = (char*)d_ws;
  u16* W1T     = (u16*)(ws);                    // O*L1*L0 bf16 = 16 MB [o][N=L1][K=L0]
  float* part  = (float*)(ws);                  // 2*B*L2 f32 = 16 MB (aliases W1T)
  u16* W2T     = (u16*)(ws + 16777216);         // O*L2*L1 bf16 = 16 MB [o][N=L2][K=L1]
  u16* Xs      = (u16*)(ws + 33554432);         // B*L0 bf16 = 4 MB (sorted)
  u16* Hs      = (u16*)(ws + 37748736);         // B*L1 bf16 = 8 MB (sorted)
  int* perm    = (int*)(ws + 46137344);         // B ints
  int* starts  = (int*)(ws + 46137344 + 8192);  // 5 ints
  int* cursors = starts + 8;                    // 4 ints

  hist_kernel<<<1, 256, 0, stream>>>(idx, B, starts, cursors);
  transpose_convert<<<dim3(L1 / 64, L0 / 64, O), 256, 0, stream>>>(W1, W1T, L0, L1);
  transpose_convert<<<dim3(L2 / 64, L1 / 64, O), 256, 0, stream>>>(W2, W2T, L1, L2);
  permute_convert<<<B, 256, 0, stream>>>(x, idx, starts, cursors, perm, Xs);

  // GEMM1: M~512/group, N=2048, K=1024, no split. 16n x 16m x 4g = 1024 blocks.
  gemm_kernel<0, 1024, 2048, 1, 16, 16><<<1024, 256, 0, stream>>>(
      Xs, W1T, b1, starts, Hs, nullptr, B);
  // GEMM2: M~512/group, N=1024, K=2048, split-K x2. 8n x 16m x 4g x 2s = 1024 blocks.
  gemm_kernel<1, 2048, 1024, 2, 8, 16><<<1024, 256, 0, stream>>>(
      Hs, W2T, nullptr, starts, nullptr, part, B);
  reduce_kernel<<<B, 256, 0, stream>>>(part, b2, perm, out, B);
}

// Round 4
// 110.858 us; speedup vs baseline: 1.3311x; 1.1224x over previous
//
#include <hip/hip_runtime.h>
#include <stdint.h>

typedef __bf16 bf16x8 __attribute__((ext_vector_type(8)));
typedef float f32x4 __attribute__((ext_vector_type(4)));
typedef unsigned short u16;
typedef const __attribute__((address_space(1))) void* as1_cvp;
typedef __attribute__((address_space(3))) void* as3_vp;

__device__ __forceinline__ u16 f2bf(float f) {
  union { float f; unsigned u; } v; v.f = f;
  unsigned r = v.u + 0x7fffu + ((v.u >> 16) & 1u);
  return (u16)(r >> 16);
}

// ---- idx histogram + exclusive scan (4 options) ----
__global__ __launch_bounds__(256) void hist_kernel(const int* __restrict__ idx, int n,
                            int* __restrict__ starts, int* __restrict__ cursors) {
  __shared__ int cnt[4];
  const int t = threadIdx.x;
  if (t < 4) { cnt[t] = 0; cursors[t] = 0; }
  __syncthreads();
  int c0 = 0, c1 = 0, c2 = 0, c3 = 0;
  for (int i = t; i < n; i += 256) {
    const int g = idx[i] & 3;
    c0 += (g == 0); c1 += (g == 1); c2 += (g == 2); c3 += (g == 3);
  }
  if (c0) atomicAdd(&cnt[0], c0);
  if (c1) atomicAdd(&cnt[1], c1);
  if (c2) atomicAdd(&cnt[2], c2);
  if (c3) atomicAdd(&cnt[3], c3);
  __syncthreads();
  if (t == 0) {
    int s = 0;
    for (int g = 0; g < 4; ++g) { starts[g] = s; s += cnt[g]; }
    starts[4] = s;
  }
}

// ---- per-row: rank within group, write perm, convert row to bf16 (sorted) ----
__global__ __launch_bounds__(256) void permute_convert(
    const float* __restrict__ x, const int* __restrict__ idx,
    const int* __restrict__ starts, int* cursors,
    int* __restrict__ perm, u16* __restrict__ Xs) {
  const int b = blockIdx.x;
  __shared__ int s_pos;
  if (threadIdx.x == 0) {
    const int g = idx[b] & 3;
    const int r = atomicAdd(&cursors[g], 1);
    const int p = starts[g] + r;
    perm[p] = b;
    s_pos = p;
  }
  __syncthreads();
  const int p = s_pos;
  const float4 v = ((const float4*)(x + (size_t)b * 1024))[threadIdx.x];
  ushort4 u;
  u.x = f2bf(v.x); u.y = f2bf(v.y); u.z = f2bf(v.z); u.w = f2bf(v.w);
  ((ushort4*)(Xs + (size_t)p * 1024))[threadIdx.x] = u;
}

// ---- both W transposes in one launch: W [O][K][N] f32 -> WT [O][N][K] bf16 ----
__global__ __launch_bounds__(256) void transpose_both(
    const float* __restrict__ W1, u16* __restrict__ W1T,
    const float* __restrict__ W2, u16* __restrict__ W2T) {
  __shared__ float tile[64][65];
  int bid = blockIdx.x;
  const float* W; u16* WT; int K, N, tx, ty, o;
  if (bid < 2048) {         // W1: K=1024, N=2048 -> 32x16x4 tiles
    W = W1; WT = W1T; K = 1024; N = 2048;
    o = bid >> 9; const int t = bid & 511; tx = t & 31; ty = t >> 5;
  } else {                  // W2: K=2048, N=1024 -> 16x32x4 tiles
    bid -= 2048;
    W = W2; WT = W2T; K = 2048; N = 1024;
    o = bid >> 9; const int t = bid & 511; tx = t & 15; ty = t >> 4;
  }
  const float* Wo = W + (size_t)o * K * N;
  u16* WTo = WT + (size_t)o * N * K;
  const int k0 = ty * 64, n0 = tx * 64;
  const int rr = threadIdx.x >> 4, cc = threadIdx.x & 15;
  #pragma unroll
  for (int j = 0; j < 4; ++j) {
    const int r = j * 16 + rr;
    const float4 v = *(const float4*)(Wo + (size_t)(k0 + r) * N + n0 + cc * 4);
    tile[r][cc * 4 + 0] = v.x; tile[r][cc * 4 + 1] = v.y;
    tile[r][cc * 4 + 2] = v.z; tile[r][cc * 4 + 3] = v.w;
  }
  __syncthreads();
  #pragma unroll
  for (int j = 0; j < 4; ++j) {
    const int nrow = j * 16 + rr;
    ushort4 u;
    u.x = f2bf(tile[cc * 4 + 0][nrow]);
    u.y = f2bf(tile[cc * 4 + 1][nrow]);
    u.z = f2bf(tile[cc * 4 + 2][nrow]);
    u.w = f2bf(tile[cc * 4 + 3][nrow]);
    *(ushort4*)(WTo + (size_t)(n0 + nrow) * K + k0 + cc * 4) = u;
  }
}

// ---- grouped GEMM: C[M,N] = A_sorted[M,K] @ WT[o][N,K]^T ----
// tile M64 x N128, BK=64, 4 waves (2x2), wave 32x64 (2x4 frags, kk-loop 2)
// Double-buffered LDS, counted vmcnt (T3/T4-min), T2 XOR swizzle (16B units).
// EPI 0: write bf16 (sorted) + bias.  EPI 1: write f32 split-K partial.
template <int EPI, int KT, int NN, int S, int NTN, int NTM>
__global__ __launch_bounds__(256) void gemm_kernel(
    const u16* __restrict__ A, const u16* __restrict__ BT,
    const float* __restrict__ bias, const int* __restrict__ starts,
    u16* __restrict__ outH, float* __restrict__ outP, int batchB) {
  // buf0: A @0 (8KB), B @8192 (16KB); buf1: A @24576, B @32768
  __shared__ char smem[49152];

  // XCD-chunked bijective swizzle (nwg % 8 == 0), n fastest -> L2 panel reuse
  const int nwg = NTN * NTM * 4 * S;
  const int q = nwg >> 3;
  const int bid = blockIdx.x;
  const int swz = (bid & 7) * q + (bid >> 3);
  const int n_t = swz % NTN;
  const int m_t = (swz / NTN) % NTM;
  const int og = swz / (NTN * NTM);
  const int o = og & 3;
  const int s = og >> 2;

  const int g0 = starts[o], g1 = starts[o + 1];
  const int m_start = g0 + m_t * 64;
  if (m_start >= g1) return;
  const int n_start = n_t * 128;
  const int kb0 = s * (KT / S);
  const u16* Bo = BT + (size_t)o * NN * KT;

  const int tid = threadIdx.x;
  const int w = tid >> 6;  // wave 0..3
  const int l = tid & 63;
  const int wm = w >> 1, wn = w & 1;
  const int l8 = l & 7, ld8 = l >> 3;

  // T2: global source column pre-swizzled so linear LDS dest holds
  // LDS[row][unit] = global[row][unit ^ (row&7)]  (16B units, 8 per 128B row)
  const int src_unit = l8 ^ (ld8 & 7);

  const u16* pA[2];
  #pragma unroll
  for (int j = 0; j < 2; ++j) {
    int r = m_start + (j * 4 + w) * 8 + ld8;
    if (r >= g1) r = g1 - 1;  // clamp (stores predicated at epilogue)
    pA[j] = A + (size_t)r * KT + kb0 + src_unit * 8;
  }
  const u16* pB[4];
  #pragma unroll
  for (int j = 0; j < 4; ++j) {
    const int nr = n_start + (j * 4 + w) * 8 + ld8;
    pB[j] = Bo + (size_t)nr * KT + kb0 + src_unit * 8;
  }

#define STAGE(dst_off)                                                         \
  {                                                                            \
    _Pragma("unroll")                                                          \
    for (int j = 0; j < 2; ++j)                                                \
      __builtin_amdgcn_global_load_lds((as1_cvp)pA[j],                         \
          (as3_vp)(smem + (dst_off) + (j * 4 + w) * 1024), 16, 0, 0);          \
    _Pragma("unroll")                                                          \
    for (int j = 0; j < 4; ++j)                                                \
      __builtin_amdgcn_global_load_lds((as1_cvp)pB[j],                         \
          (as3_vp)(smem + (dst_off) + 8192 + (j * 4 + w) * 1024), 16, 0, 0);   \
    _Pragma("unroll") for (int j = 0; j < 2; ++j) pA[j] += 64;                 \
    _Pragma("unroll") for (int j = 0; j < 4; ++j) pB[j] += 64;                 \
  }

  // fragment read byte offsets (within A/B tile), T2 read-side XOR:
  // row = base + (l&15) (bases are x16 so row&7 == l&7); unit = kk*4 + (l>>4)
  const int lrow = l & 15;
  const int lx = l & 7;
  const int lu = l >> 4;
  int offA[2][2], offB[4][2];
  #pragma unroll
  for (int a = 0; a < 2; ++a)
    #pragma unroll
    for (int kk = 0; kk < 2; ++kk)
      offA[a][kk] = (wm * 32 + a * 16 + lrow) * 128 + (((kk * 4 + lu) ^ lx) << 4);
  #pragma unroll
  for (int b = 0; b < 4; ++b)
    #pragma unroll
    for (int kk = 0; kk < 2; ++kk)
      offB[b][kk] = (wn * 64 + b * 16 + lrow) * 128 + (((kk * 4 + lu) ^ lx) << 4);

  f32x4 acc[2][4] = {};

  const int nK = (KT / S) >> 6;
  STAGE(0);  // prologue: tile 0 -> buf0
  for (int kt = 0; kt < nK; ++kt) {
    const int cur = (kt & 1) * 24576;
    if (kt + 1 < nK) {
      STAGE(24576 - cur);  // next tile -> other buffer (loads stay in flight)
      asm volatile("s_waitcnt vmcnt(6)" ::: "memory");  // prior stage landed
    } else {
      asm volatile("s_waitcnt vmcnt(0)" ::: "memory");
    }
    __builtin_amdgcn_s_barrier();  // buf[cur] valid for all waves

    bf16x8 af[2][2], bfr[4][2];
    #pragma unroll
    for (int a = 0; a < 2; ++a)
      #pragma unroll
      for (int kk = 0; kk < 2; ++kk)
        af[a][kk] = *(const bf16x8*)(smem + cur + offA[a][kk]);
    #pragma unroll
    for (int b = 0; b < 4; ++b)
      #pragma unroll
      for (int kk = 0; kk < 2; ++kk)
        bfr[b][kk] = *(const bf16x8*)(smem + cur + 8192 + offB[b][kk]);
    asm volatile("s_waitcnt lgkmcnt(0)" ::: "memory");  // my reads done
    __builtin_amdgcn_s_barrier();  // all reads done -> next STAGE may overwrite

    #pragma unroll
    for (int kk = 0; kk < 2; ++kk)
      #pragma unroll
      for (int a = 0; a < 2; ++a)
        #pragma unroll
        for (int b = 0; b < 4; ++b)
          acc[a][b] = __builtin_amdgcn_mfma_f32_16x16x32_bf16(af[a][kk], bfr[b][kk], acc[a][b], 0, 0, 0);
  }
#undef STAGE

  // epilogue: C/D layout col = l&15, row = (l>>4)*4 + r  [m89-verified]
  const int col_l = l & 15;
  const int row_l = (l >> 4) << 2;
  #pragma unroll
  for (int a = 0; a < 2; ++a) {
    #pragma unroll
    for (int b = 0; b < 4; ++b) {
      const int n = n_start + wn * 64 + b * 16 + col_l;
      float bv = 0.f;
      if (EPI == 0) bv = bias[n];
      #pragma unroll
      for (int r = 0; r < 4; ++r) {
        const int p = m_start + wm * 32 + a * 16 + row_l + r;
        if (p < g1) {
          if (EPI == 0) {
            outH[(size_t)p * NN + n] = f2bf(acc[a][b][r] + bv);
          } else {
            outP[((size_t)(s * batchB + p)) * NN + n] = acc[a][b][r];
          }
        }
      }
    }
  }
}

// ---- split-K reduce + bias + scatter (deterministic fixed-order adds) ----
__global__ __launch_bounds__(256) void reduce_kernel(
    const float* __restrict__ part, const float* __restrict__ b2,
    const int* __restrict__ perm, float* __restrict__ out, int batchB) {
  const int p = blockIdx.x;
  const int t = threadIdx.x;
  const float4 v0 = ((const float4*)(part + (size_t)p * 1024))[t];
  const float4 v1 = ((const float4*)(part + (size_t)(batchB + p) * 1024))[t];
  const float4 bv = ((const float4*)b2)[t];
  float4 r;
  r.x = v0.x + v1.x + bv.x;
  r.y = v0.y + v1.y + bv.y;
  r.z = v0.z + v1.z + bv.z;
  r.w = v0.w + v1.w + bv.w;
  ((float4*)(out + (size_t)perm[p] * 1024))[t] = r;
}

extern "C" void kernel_launch(void* const* d_in, const int* in_sizes, int n_in,
                              void* d_out, int out_size, void* d_ws, size_t ws_size,
                              hipStream_t stream) {
  (void)n_in; (void)out_size; (void)ws_size;
  const float* x   = (const float*)d_in[0];
  const int*   idx = (const int*)d_in[1];
  const float* W1  = (const float*)d_in[2];
  const float* b1  = (const float*)d_in[3];
  const float* W2  = (const float*)d_in[4];
  const float* b2  = (const float*)d_in[5];
  float* out = (float*)d_out;

  const int B = in_sizes[1];  // 2048

  // workspace layout (44.05 MB; part aliases W1T which is dead after GEMM1)
  char* ws = (char*)d_ws;
  u16* W1T     = (u16*)(ws);                    // 16 MB [o][N=2048][K=1024]
  float* part  = (float*)(ws);                  // 2*B*1024 f32 = 16 MB (aliases W1T)
  u16* W2T     = (u16*)(ws + 16777216);         // 16 MB [o][N=1024][K=2048]
  u16* Xs      = (u16*)(ws + 33554432);         // B*1024 bf16 = 4 MB (sorted)
  u16* Hs      = (u16*)(ws + 37748736);         // B*2048 bf16 = 8 MB (sorted)
  int* perm    = (int*)(ws + 46137344);         // B ints
  int* starts  = (int*)(ws + 46137344 + 8192);  // 5 ints
  int* cursors = starts + 8;                    // 4 ints

  hist_kernel<<<1, 256, 0, stream>>>(idx, B, starts, cursors);
  transpose_both<<<4096, 256, 0, stream>>>(W1, W1T, W2, W2T);
  permute_convert<<<B, 256, 0, stream>>>(x, idx, starts, cursors, perm, Xs);

  // GEMM1: N=2048, K=1024, no split. 16n x 16m x 4g = 1024 blocks.
  gemm_kernel<0, 1024, 2048, 1, 16, 16><<<1024, 256, 0, stream>>>(
      Xs, W1T, b1, starts, Hs, nullptr, B);
  // GEMM2: N=1024, K=2048, split-K x2. 8n x 16m x 4g x 2s = 1024 blocks.
  gemm_kernel<1, 2048, 1024, 2, 8, 16><<<1024, 256, 0, stream>>>(
      Hs, W2T, nullptr, starts, nullptr, part, B);
  reduce_kernel<<<B, 256, 0, stream>>>(part, b2, perm, out, B);
}